// Round 5
// baseline (629.784 us; speedup 1.0000x reference)
//
#include <hip/hip_runtime.h>
#include <hip/hip_bf16.h>

__device__ __forceinline__ void loadrow10(float* r, const float* p) {
  float4 a = *(const float4*)p;
  float4 b = *(const float4*)(p + 4);
  float2 c = *(const float2*)(p + 8);
  r[0]=a.x; r[1]=a.y; r[2]=a.z; r[3]=a.w;
  r[4]=b.x; r[5]=b.y; r[6]=b.z; r[7]=b.w;
  r[8]=c.x; r[9]=c.y;
}
__device__ __forceinline__ void loadrow8(float* r, const float* p) {
  float4 a = *(const float4*)p;
  float4 b = *(const float4*)(p + 4);
  r[0]=a.x; r[1]=a.y; r[2]=a.z; r[3]=a.w;
  r[4]=b.x; r[5]=b.y; r[6]=b.z; r[7]=b.w;
}

// ---------------------------------------------------------------------------
// K1: conv1 (3->8, 7x7) + maxpool2 + relu.
// 256 thr = 8 px2 x 32 py; each thread computes 2 pooled-x outputs
// (4 conv cols x 2 conv rows x 8 ch) -> 8 FMAs per scalar weight load.
// Pooled tile 16x32. Input tile s_in[3][70][38] (31.9 KB).
// Weights read via wave-uniform strided indices -> s_load (R2-proven path).
// ---------------------------------------------------------------------------
__global__ __launch_bounds__(256) void k1_conv_pool(
    const float* __restrict__ x, const float* __restrict__ w,
    const float* __restrict__ bias, float* __restrict__ out) {
  __shared__ float s_in[3 * 70 * 38];
  const int b = blockIdx.z;
  const int PX0 = blockIdx.x * 16, PY0 = blockIdx.y * 32;
  const int X0 = PX0 * 2, Y0 = PY0 * 2;
  const int tid = threadIdx.x;

  for (int idx = tid; idx < 3 * 70 * 38; idx += 256) {
    int c = idx / (70 * 38), rem = idx % (70 * 38);
    int iy = rem / 38, ixx = rem % 38;
    int gy = Y0 + iy, gxx = X0 + ixx;
    float v = 0.f;
    if (gy < 224 && gxx < 224) v = x[((b * 3 + c) * 224 + gy) * 224 + gxx];
    s_in[idx] = v;
  }
  __syncthreads();

  const int px2 = tid & 7, py = tid >> 3;  // px2: 0..7, py: 0..31
  // acc[o][j]: j = ylocal*4 + xlocal, conv pos (2py+ylocal, 4px2+xlocal)
  float acc[8][8];
#pragma unroll
  for (int o = 0; o < 8; ++o)
#pragma unroll
    for (int j = 0; j < 8; ++j) acc[o][j] = 0.f;

  for (int c = 0; c < 3; ++c) {
    const float* base = &s_in[c * 2660 + (2 * py) * 38 + 4 * px2];
    float rows[2][10];
    loadrow10(rows[0], base);
#pragma unroll
    for (int ky = 0; ky < 7; ++ky) {
      loadrow10(rows[(ky + 1) & 1], base + (ky + 1) * 38);
      const float* r0 = rows[ky & 1];        // input row 2py+ky   (conv y0)
      const float* r1 = rows[(ky + 1) & 1];  // input row 2py+ky+1 (conv y1)
#pragma unroll
      for (int kx = 0; kx < 7; ++kx) {
#pragma unroll
        for (int o = 0; o < 8; ++o) {
          float wv = w[o * 147 + c * 49 + ky * 7 + kx];  // uniform -> s_load
          acc[o][0] = fmaf(r0[kx + 0], wv, acc[o][0]);
          acc[o][1] = fmaf(r0[kx + 1], wv, acc[o][1]);
          acc[o][2] = fmaf(r0[kx + 2], wv, acc[o][2]);
          acc[o][3] = fmaf(r0[kx + 3], wv, acc[o][3]);
          acc[o][4] = fmaf(r1[kx + 0], wv, acc[o][4]);
          acc[o][5] = fmaf(r1[kx + 1], wv, acc[o][5]);
          acc[o][6] = fmaf(r1[kx + 2], wv, acc[o][6]);
          acc[o][7] = fmaf(r1[kx + 3], wv, acc[o][7]);
        }
      }
    }
  }

  const int Y = PY0 + py;
  if (Y < 109) {
#pragma unroll
    for (int xp = 0; xp < 2; ++xp) {
      int X = PX0 + 2 * px2 + xp;
      if (X < 109) {
#pragma unroll
        for (int o = 0; o < 8; ++o) {
          float m = fmaxf(fmaxf(acc[o][2 * xp], acc[o][2 * xp + 1]),
                          fmaxf(acc[o][4 + 2 * xp], acc[o][4 + 2 * xp + 1]));
          m += bias[o];
          out[((b * 8 + o) * 109 + Y) * 109 + X] = fmaxf(m, 0.f);
        }
      }
    }
  }
}

// ---------------------------------------------------------------------------
// K2: conv2 (8->10, 5x5) + maxpool2 + relu.
// 192 thr (169 active) = 13 px2 x 13 py; thread = 2 pooled-x outputs
// (4 conv cols x 2 conv rows x 10 ch). Pooled tile 26x13.
// Input tile s_in[8][30][56] (53.8 KB); all staging reads in-bounds.
// ---------------------------------------------------------------------------
__global__ __launch_bounds__(192) void k2_conv_pool(
    const float* __restrict__ in, const float* __restrict__ w,
    const float* __restrict__ bias, float* __restrict__ out) {
  __shared__ float s_in[8 * 30 * 56];
  const int b = blockIdx.z;
  const int PX0 = blockIdx.x * 26, PY0 = blockIdx.y * 13;
  const int X0 = PX0 * 2, Y0 = PY0 * 2;
  const int tid = threadIdx.x;

  for (int idx = tid; idx < 8 * 30 * 56; idx += 192) {
    int c = idx / (30 * 56), rem = idx % (30 * 56);
    int iy = rem / 56, ixx = rem % 56;
    s_in[idx] = in[((b * 8 + c) * 109 + Y0 + iy) * 109 + X0 + ixx];
  }
  __syncthreads();

  if (tid >= 169) return;
  const int px2 = tid % 13, py = tid / 13;
  float acc[10][8];
#pragma unroll
  for (int o = 0; o < 10; ++o)
#pragma unroll
    for (int j = 0; j < 8; ++j) acc[o][j] = 0.f;

  for (int c = 0; c < 8; ++c) {
    const float* base = &s_in[c * 1680 + (2 * py) * 56 + 4 * px2];
    float rows[2][8];
    loadrow8(rows[0], base);
#pragma unroll
    for (int ky = 0; ky < 5; ++ky) {
      loadrow8(rows[(ky + 1) & 1], base + (ky + 1) * 56);
      const float* r0 = rows[ky & 1];
      const float* r1 = rows[(ky + 1) & 1];
#pragma unroll
      for (int kx = 0; kx < 5; ++kx) {
#pragma unroll
        for (int o = 0; o < 10; ++o) {
          float wv = w[o * 200 + c * 25 + ky * 5 + kx];  // uniform -> s_load
          acc[o][0] = fmaf(r0[kx + 0], wv, acc[o][0]);
          acc[o][1] = fmaf(r0[kx + 1], wv, acc[o][1]);
          acc[o][2] = fmaf(r0[kx + 2], wv, acc[o][2]);
          acc[o][3] = fmaf(r0[kx + 3], wv, acc[o][3]);
          acc[o][4] = fmaf(r1[kx + 0], wv, acc[o][4]);
          acc[o][5] = fmaf(r1[kx + 1], wv, acc[o][5]);
          acc[o][6] = fmaf(r1[kx + 2], wv, acc[o][6]);
          acc[o][7] = fmaf(r1[kx + 3], wv, acc[o][7]);
        }
      }
    }
  }

  const int Y = PY0 + py;
#pragma unroll
  for (int xp = 0; xp < 2; ++xp) {
    int X = PX0 + 2 * px2 + xp;
#pragma unroll
    for (int o = 0; o < 10; ++o) {
      float m = fmaxf(fmaxf(acc[o][2 * xp], acc[o][2 * xp + 1]),
                      fmaxf(acc[o][4 + 2 * xp], acc[o][4 + 2 * xp + 1]));
      m += bias[o];
      out[((b * 10 + o) * 52 + Y) * 52 + X] = fmaxf(m, 0.f);
    }
  }
}

// ---------------------------------------------------------------------------
// K3: fc1 split-K partial GEMM, 256 blocks x 2 chunks of 64.
// ---------------------------------------------------------------------------
__global__ __launch_bounds__(256) void k3_fc1_partial(
    const float* __restrict__ xs, const float* __restrict__ w,
    float* __restrict__ part) {
  __shared__ float sA[128 * 64];
  __shared__ float sW[64 * 33];
  const int p = blockIdx.x;
  const int tid = threadIdx.x;
  const int n = tid & 31, bg = tid >> 5;
  float acc[16];
#pragma unroll
  for (int i = 0; i < 16; ++i) acc[i] = 0.f;

  for (int ch = 0; ch < 2; ++ch) {
    const int k0 = p * 128 + ch * 64;
    __syncthreads();
    for (int idx = tid; idx < 8192; idx += 256) {
      int bb = idx >> 6, k = idx & 63;
      int gk = k0 + k;
      sA[idx] = (gk < 27040) ? xs[bb * 27040 + gk] : 0.f;
    }
    for (int idx = tid; idx < 2048; idx += 256) {
      int nn = idx >> 6, k = idx & 63;
      int gk = k0 + k;
      sW[k * 33 + nn] = (gk < 27040) ? w[nn * 27040 + gk] : 0.f;
    }
    __syncthreads();
    for (int k = 0; k < 64; k += 4) {
      float w0 = sW[(k + 0) * 33 + n];
      float w1 = sW[(k + 1) * 33 + n];
      float w2 = sW[(k + 2) * 33 + n];
      float w3 = sW[(k + 3) * 33 + n];
#pragma unroll
      for (int i = 0; i < 16; ++i) {
        float4 a = *(const float4*)&sA[(bg * 16 + i) * 64 + k];
        acc[i] = fmaf(a.x, w0, acc[i]);
        acc[i] = fmaf(a.y, w1, acc[i]);
        acc[i] = fmaf(a.z, w2, acc[i]);
        acc[i] = fmaf(a.w, w3, acc[i]);
      }
    }
  }
#pragma unroll
  for (int i = 0; i < 16; ++i)
    part[p * 4096 + (bg * 16 + i) * 32 + n] = acc[i];
}

// ---------------------------------------------------------------------------
// K4: reduce 256 partials -> h = relu(C + b1). 512 blocks, shfl-reduce.
// ---------------------------------------------------------------------------
__global__ __launch_bounds__(256) void k4_reduce(
    const float* __restrict__ part, const float* __restrict__ b1,
    float* __restrict__ h) {
  const int lane = threadIdx.x & 31;
  const int eloc = threadIdx.x >> 5;
  const int e = blockIdx.x * 8 + eloc;
  float s = 0.f;
#pragma unroll
  for (int pc = 0; pc < 8; ++pc) s += part[(pc * 32 + lane) * 4096 + e];
#pragma unroll
  for (int off = 16; off > 0; off >>= 1) s += __shfl_down(s, off, 32);
  if (lane == 0) h[e] = fmaxf(s + b1[e & 31], 0.f);
}

// ---------------------------------------------------------------------------
// K5: theta (recomputed per block) + fused affine_grid + bilinear sample.
// ---------------------------------------------------------------------------
__global__ __launch_bounds__(256) void k5_sample(
    const float* __restrict__ x, const float* __restrict__ h,
    const float* __restrict__ w2, const float* __restrict__ b2,
    float* __restrict__ out) {
  __shared__ float th[6];
  const int b = blockIdx.z;
  if (threadIdx.x < 6) {
    int j = threadIdx.x;
    float s = b2[j];
    for (int m = 0; m < 32; ++m) s = fmaf(h[b * 32 + m], w2[j * 32 + m], s);
    th[j] = s;
  }
  __syncthreads();

  const int pix = blockIdx.x * 256 + threadIdx.x;
  const int hh = pix / 224, ww = pix % 224;
  const float step = 2.0f / 223.0f;
  float gx = ww * step - 1.0f, gy = hh * step - 1.0f;
  float tx = th[0] * gx + th[1] * gy + th[2];
  float ty = th[3] * gx + th[4] * gy + th[5];
  float ix = (tx + 1.0f) * 0.5f * 223.0f;
  float iy = (ty + 1.0f) * 0.5f * 223.0f;
  float x0 = floorf(ix), y0 = floorf(iy);
  float x1 = x0 + 1.f, y1 = y0 + 1.f;
  float wx1 = ix - x0, wx0 = x1 - ix;
  float wy1 = iy - y0, wy0 = y1 - iy;
  float w00 = wx0 * wy0, w01 = wx1 * wy0, w10 = wx0 * wy1, w11 = wx1 * wy1;
  bool vx0 = (x0 >= 0.f) && (x0 <= 223.f);
  bool vx1 = (x1 >= 0.f) && (x1 <= 223.f);
  bool vy0 = (y0 >= 0.f) && (y0 <= 223.f);
  bool vy1 = (y1 >= 0.f) && (y1 <= 223.f);
  w00 = (vx0 && vy0) ? w00 : 0.f;
  w01 = (vx1 && vy0) ? w01 : 0.f;
  w10 = (vx0 && vy1) ? w10 : 0.f;
  w11 = (vx1 && vy1) ? w11 : 0.f;
  int xi0 = (int)fminf(fmaxf(x0, 0.f), 223.f);
  int xi1 = (int)fminf(fmaxf(x1, 0.f), 223.f);
  int yi0 = (int)fminf(fmaxf(y0, 0.f), 223.f);
  int yi1 = (int)fminf(fmaxf(y1, 0.f), 223.f);
#pragma unroll
  for (int c = 0; c < 3; ++c) {
    const float* img = x + (size_t)((b * 3 + c) * 224) * 224;
    float v = img[yi0 * 224 + xi0] * w00 + img[yi0 * 224 + xi1] * w01 +
              img[yi1 * 224 + xi0] * w10 + img[yi1 * 224 + xi1] * w11;
    out[((b * 3 + c) * 224 + hh) * 224 + ww] = v;
  }
}

extern "C" void kernel_launch(void* const* d_in, const int* in_sizes, int n_in,
                              void* d_out, int out_size, void* d_ws,
                              size_t ws_size, hipStream_t stream) {
  const float* x   = (const float*)d_in[0];
  const float* w1  = (const float*)d_in[1];
  const float* b1  = (const float*)d_in[2];
  const float* w2  = (const float*)d_in[3];
  const float* b2  = (const float*)d_in[4];
  const float* fw1 = (const float*)d_in[5];
  const float* fb1 = (const float*)d_in[6];
  const float* fw2 = (const float*)d_in[7];
  const float* fb2 = (const float*)d_in[8];
  float* out = (float*)d_out;

  float* ws   = (float*)d_ws;
  float* out1 = ws;                    // [128,8,109,109] = 12,166,144 f32
  float* xs   = out1 + 12166144;       // [128,10,52,52]  =  3,461,120 f32
  float* part = xs + 3461120;          // [256,128,32]    =  1,048,576 f32
  float* hbuf = part + 1048576;        // [128,32]        =      4,096 f32

  k1_conv_pool<<<dim3(7, 4, 128), 256, 0, stream>>>(x, w1, b1, out1);
  k2_conv_pool<<<dim3(2, 4, 128), 192, 0, stream>>>(out1, w2, b2, xs);
  k3_fc1_partial<<<256, 256, 0, stream>>>(xs, fw1, part);
  k4_reduce<<<512, 256, 0, stream>>>(part, fb1, hbuf);
  k5_sample<<<dim3(196, 1, 128), 256, 0, stream>>>(x, hbuf, fw2, fb2, out);
}

// Round 6
// 346.200 us; speedup vs baseline: 1.8191x; 1.8191x over previous
//
#include <hip/hip_runtime.h>
#include <hip/hip_bf16.h>

__device__ __forceinline__ void loadrow8(float* r, const float* p) {
#pragma unroll
  for (int i = 0; i < 4; ++i) {
    float2 t = *(const float2*)(p + 2 * i);
    r[2 * i] = t.x; r[2 * i + 1] = t.y;
  }
}
__device__ __forceinline__ void loadrow6(float* r, const float* p) {
#pragma unroll
  for (int i = 0; i < 3; ++i) {
    float2 t = *(const float2*)(p + 2 * i);
    r[2 * i] = t.x; r[2 * i + 1] = t.y;
  }
}

// ---------------------------------------------------------------------------
// K1: conv1 (3->8, 7x7) + maxpool2 + relu. 256 thr = 16x16 pool tile
// (R2 shape: acc[8][4]=32 regs, no spill). Weights: per-(c,ky) batch of 56
// uniform scalar loads hoisted ahead of the 224-FMA block -> one lgkm wait.
// ---------------------------------------------------------------------------
__global__ __launch_bounds__(256) void k1_conv_pool(
    const float* __restrict__ x, const float* __restrict__ w,
    const float* __restrict__ bias, float* __restrict__ out) {
  __shared__ float s_in[3 * 38 * 38];
  const int b = blockIdx.z;
  const int PX0 = blockIdx.x * 16, PY0 = blockIdx.y * 16;
  const int X0 = PX0 * 2, Y0 = PY0 * 2;
  const int tid = threadIdx.x;

  for (int idx = tid; idx < 3 * 38 * 38; idx += 256) {
    int c = idx / (38 * 38), rem = idx % (38 * 38);
    int iy = rem / 38, ixx = rem % 38;
    int gy = Y0 + iy, gxx = X0 + ixx;
    float v = 0.f;
    if (gy < 224 && gxx < 224) v = x[((b * 3 + c) * 224 + gy) * 224 + gxx];
    s_in[idx] = v;
  }
  __syncthreads();

  const int py = tid >> 4, px = tid & 15;
  float acc[8][4];
#pragma unroll
  for (int o = 0; o < 8; ++o)
    acc[o][0] = acc[o][1] = acc[o][2] = acc[o][3] = 0.f;

  for (int c = 0; c < 3; ++c) {
    const float* base = &s_in[c * 1444 + 2 * px];
    const float* wc = w + c * 49;
    float rows[2][8];
    loadrow8(rows[0], base + (2 * py) * 38);
#pragma unroll
    for (int ky = 0; ky < 7; ++ky) {
      // batched uniform weight prefetch for this (c,ky): 56 s_loads, hoisted
      float wk[8][7];
#pragma unroll
      for (int o = 0; o < 8; ++o)
#pragma unroll
        for (int kx = 0; kx < 7; ++kx)
          wk[o][kx] = wc[o * 147 + ky * 7 + kx];
      loadrow8(rows[(ky + 1) & 1], base + (2 * py + ky + 1) * 38);
      const float* r0 = rows[ky & 1];
      const float* r1 = rows[(ky + 1) & 1];
#pragma unroll
      for (int kx = 0; kx < 7; ++kx) {
        float i00 = r0[kx], i01 = r0[kx + 1];
        float i10 = r1[kx], i11 = r1[kx + 1];
#pragma unroll
        for (int o = 0; o < 8; ++o) {
          float wv = wk[o][kx];
          acc[o][0] = fmaf(i00, wv, acc[o][0]);
          acc[o][1] = fmaf(i01, wv, acc[o][1]);
          acc[o][2] = fmaf(i10, wv, acc[o][2]);
          acc[o][3] = fmaf(i11, wv, acc[o][3]);
        }
      }
    }
  }

  int opy = PY0 + py, opx = PX0 + px;
  if (opy < 109 && opx < 109) {
#pragma unroll
    for (int o = 0; o < 8; ++o) {
      float m = fmaxf(fmaxf(acc[o][0], acc[o][1]), fmaxf(acc[o][2], acc[o][3]));
      m += bias[o];
      out[((b * 8 + o) * 109 + opy) * 109 + opx] = fmaxf(m, 0.f);
    }
  }
}

// ---------------------------------------------------------------------------
// K2: conv2 (8->10, 5x5) + maxpool2 + relu. 13x13 pool tile (R2 shape),
// per-(c,ky) batched uniform weight prefetch (50 loads).
// ---------------------------------------------------------------------------
__global__ __launch_bounds__(192) void k2_conv_pool(
    const float* __restrict__ in, const float* __restrict__ w,
    const float* __restrict__ bias, float* __restrict__ out) {
  __shared__ float s_in[8 * 30 * 30];
  const int b = blockIdx.z;
  const int PX0 = blockIdx.x * 13, PY0 = blockIdx.y * 13;
  const int X0 = PX0 * 2, Y0 = PY0 * 2;
  const int tid = threadIdx.x;

  for (int idx = tid; idx < 8 * 30 * 30; idx += 192) {
    int c = idx / 900, rem = idx % 900;
    int iy = rem / 30, ixx = rem % 30;
    s_in[idx] = in[((b * 8 + c) * 109 + Y0 + iy) * 109 + X0 + ixx];
  }
  __syncthreads();

  if (tid >= 169) return;
  const int py = tid / 13, px = tid % 13;
  float acc[10][4];
#pragma unroll
  for (int o = 0; o < 10; ++o)
    acc[o][0] = acc[o][1] = acc[o][2] = acc[o][3] = 0.f;

  for (int c = 0; c < 8; ++c) {
    const float* base = &s_in[c * 900 + 2 * px];
    const float* wc = w + c * 25;
    float rows[2][6];
    loadrow6(rows[0], base + (2 * py) * 30);
#pragma unroll
    for (int ky = 0; ky < 5; ++ky) {
      float wk[10][5];
#pragma unroll
      for (int o = 0; o < 10; ++o)
#pragma unroll
        for (int kx = 0; kx < 5; ++kx)
          wk[o][kx] = wc[o * 200 + ky * 5 + kx];
      loadrow6(rows[(ky + 1) & 1], base + (2 * py + ky + 1) * 30);
      const float* r0 = rows[ky & 1];
      const float* r1 = rows[(ky + 1) & 1];
#pragma unroll
      for (int kx = 0; kx < 5; ++kx) {
        float i00 = r0[kx], i01 = r0[kx + 1];
        float i10 = r1[kx], i11 = r1[kx + 1];
#pragma unroll
        for (int o = 0; o < 10; ++o) {
          float wv = wk[o][kx];
          acc[o][0] = fmaf(i00, wv, acc[o][0]);
          acc[o][1] = fmaf(i01, wv, acc[o][1]);
          acc[o][2] = fmaf(i10, wv, acc[o][2]);
          acc[o][3] = fmaf(i11, wv, acc[o][3]);
        }
      }
    }
  }

  int opy = PY0 + py, opx = PX0 + px;
#pragma unroll
  for (int o = 0; o < 10; ++o) {
    float m = fmaxf(fmaxf(acc[o][0], acc[o][1]), fmaxf(acc[o][2], acc[o][3]));
    m += bias[o];
    out[((b * 10 + o) * 52 + opy) * 52 + opx] = fmaxf(m, 0.f);
  }
}

// ---------------------------------------------------------------------------
// K3: fc1 split-K partial GEMM, 256 blocks x 2 chunks of 64.
// ---------------------------------------------------------------------------
__global__ __launch_bounds__(256) void k3_fc1_partial(
    const float* __restrict__ xs, const float* __restrict__ w,
    float* __restrict__ part) {
  __shared__ float sA[128 * 64];
  __shared__ float sW[64 * 33];
  const int p = blockIdx.x;
  const int tid = threadIdx.x;
  const int n = tid & 31, bg = tid >> 5;
  float acc[16];
#pragma unroll
  for (int i = 0; i < 16; ++i) acc[i] = 0.f;

  for (int ch = 0; ch < 2; ++ch) {
    const int k0 = p * 128 + ch * 64;
    __syncthreads();
    for (int idx = tid; idx < 8192; idx += 256) {
      int bb = idx >> 6, k = idx & 63;
      int gk = k0 + k;
      sA[idx] = (gk < 27040) ? xs[bb * 27040 + gk] : 0.f;
    }
    for (int idx = tid; idx < 2048; idx += 256) {
      int nn = idx >> 6, k = idx & 63;
      int gk = k0 + k;
      sW[k * 33 + nn] = (gk < 27040) ? w[nn * 27040 + gk] : 0.f;
    }
    __syncthreads();
    for (int k = 0; k < 64; k += 4) {
      float w0 = sW[(k + 0) * 33 + n];
      float w1 = sW[(k + 1) * 33 + n];
      float w2 = sW[(k + 2) * 33 + n];
      float w3 = sW[(k + 3) * 33 + n];
#pragma unroll
      for (int i = 0; i < 16; ++i) {
        float4 a = *(const float4*)&sA[(bg * 16 + i) * 64 + k];
        acc[i] = fmaf(a.x, w0, acc[i]);
        acc[i] = fmaf(a.y, w1, acc[i]);
        acc[i] = fmaf(a.z, w2, acc[i]);
        acc[i] = fmaf(a.w, w3, acc[i]);
      }
    }
  }
#pragma unroll
  for (int i = 0; i < 16; ++i)
    part[p * 4096 + (bg * 16 + i) * 32 + n] = acc[i];
}

// ---------------------------------------------------------------------------
// K4: reduce 256 partials -> h = relu(C + b1). 512 blocks, shfl-reduce.
// ---------------------------------------------------------------------------
__global__ __launch_bounds__(256) void k4_reduce(
    const float* __restrict__ part, const float* __restrict__ b1,
    float* __restrict__ h) {
  const int lane = threadIdx.x & 31;
  const int eloc = threadIdx.x >> 5;
  const int e = blockIdx.x * 8 + eloc;
  float s = 0.f;
#pragma unroll
  for (int pc = 0; pc < 8; ++pc) s += part[(pc * 32 + lane) * 4096 + e];
#pragma unroll
  for (int off = 16; off > 0; off >>= 1) s += __shfl_down(s, off, 32);
  if (lane == 0) h[e] = fmaxf(s + b1[e & 31], 0.f);
}

// ---------------------------------------------------------------------------
// K5: theta (recomputed per block) + fused affine_grid + bilinear sample.
// ---------------------------------------------------------------------------
__global__ __launch_bounds__(256) void k5_sample(
    const float* __restrict__ x, const float* __restrict__ h,
    const float* __restrict__ w2, const float* __restrict__ b2,
    float* __restrict__ out) {
  __shared__ float th[6];
  const int b = blockIdx.z;
  if (threadIdx.x < 6) {
    int j = threadIdx.x;
    float s = b2[j];
    for (int m = 0; m < 32; ++m) s = fmaf(h[b * 32 + m], w2[j * 32 + m], s);
    th[j] = s;
  }
  __syncthreads();

  const int pix = blockIdx.x * 256 + threadIdx.x;
  const int hh = pix / 224, ww = pix % 224;
  const float step = 2.0f / 223.0f;
  float gx = ww * step - 1.0f, gy = hh * step - 1.0f;
  float tx = th[0] * gx + th[1] * gy + th[2];
  float ty = th[3] * gx + th[4] * gy + th[5];
  float ix = (tx + 1.0f) * 0.5f * 223.0f;
  float iy = (ty + 1.0f) * 0.5f * 223.0f;
  float x0 = floorf(ix), y0 = floorf(iy);
  float x1 = x0 + 1.f, y1 = y0 + 1.f;
  float wx1 = ix - x0, wx0 = x1 - ix;
  float wy1 = iy - y0, wy0 = y1 - iy;
  float w00 = wx0 * wy0, w01 = wx1 * wy0, w10 = wx0 * wy1, w11 = wx1 * wy1;
  bool vx0 = (x0 >= 0.f) && (x0 <= 223.f);
  bool vx1 = (x1 >= 0.f) && (x1 <= 223.f);
  bool vy0 = (y0 >= 0.f) && (y0 <= 223.f);
  bool vy1 = (y1 >= 0.f) && (y1 <= 223.f);
  w00 = (vx0 && vy0) ? w00 : 0.f;
  w01 = (vx1 && vy0) ? w01 : 0.f;
  w10 = (vx0 && vy1) ? w10 : 0.f;
  w11 = (vx1 && vy1) ? w11 : 0.f;
  int xi0 = (int)fminf(fmaxf(x0, 0.f), 223.f);
  int xi1 = (int)fminf(fmaxf(x1, 0.f), 223.f);
  int yi0 = (int)fminf(fmaxf(y0, 0.f), 223.f);
  int yi1 = (int)fminf(fmaxf(y1, 0.f), 223.f);
#pragma unroll
  for (int c = 0; c < 3; ++c) {
    const float* img = x + (size_t)((b * 3 + c) * 224) * 224;
    float v = img[yi0 * 224 + xi0] * w00 + img[yi0 * 224 + xi1] * w01 +
              img[yi1 * 224 + xi0] * w10 + img[yi1 * 224 + xi1] * w11;
    out[((b * 3 + c) * 224 + hh) * 224 + ww] = v;
  }
}

extern "C" void kernel_launch(void* const* d_in, const int* in_sizes, int n_in,
                              void* d_out, int out_size, void* d_ws,
                              size_t ws_size, hipStream_t stream) {
  const float* x   = (const float*)d_in[0];
  const float* w1  = (const float*)d_in[1];
  const float* b1  = (const float*)d_in[2];
  const float* w2  = (const float*)d_in[3];
  const float* b2  = (const float*)d_in[4];
  const float* fw1 = (const float*)d_in[5];
  const float* fb1 = (const float*)d_in[6];
  const float* fw2 = (const float*)d_in[7];
  const float* fb2 = (const float*)d_in[8];
  float* out = (float*)d_out;

  float* ws   = (float*)d_ws;
  float* out1 = ws;                    // [128,8,109,109] = 12,166,144 f32
  float* xs   = out1 + 12166144;       // [128,10,52,52]  =  3,461,120 f32
  float* part = xs + 3461120;          // [256,128,32]    =  1,048,576 f32
  float* hbuf = part + 1048576;        // [128,32]        =      4,096 f32

  k1_conv_pool<<<dim3(7, 7, 128), 256, 0, stream>>>(x, w1, b1, out1);
  k2_conv_pool<<<dim3(4, 4, 128), 192, 0, stream>>>(out1, w2, b2, xs);
  k3_fc1_partial<<<256, 256, 0, stream>>>(xs, fw1, part);
  k4_reduce<<<512, 256, 0, stream>>>(part, fb1, hbuf);
  k5_sample<<<dim3(196, 1, 128), 256, 0, stream>>>(x, hbuf, fw2, fb2, out);
}